// Round 6
// baseline (499.883 us; speedup 1.0000x reference)
//
#include <hip/hip_runtime.h>
#include <cstdint>
#include <cmath>

// Problem constants
#define EDIM 1024
#define SEQ 2048
#define BATCH 4
#define NHEAD 16
#define HDIM 64
#define MLPD 4096
#define ROWS 8192  // BATCH*SEQ

typedef unsigned short u16;
typedef __attribute__((ext_vector_type(8))) short short8;   // 8 bf16 = 4 VGPRs (MFMA A/B frag)
typedef __attribute__((ext_vector_type(4))) float floatx4;  // MFMA C/D frag

#define AS1 __attribute__((address_space(1)))
#define AS3 __attribute__((address_space(3)))

// exp(s*0.125) = 2^(s*0.125*log2e); fold scale into Q at GEMM epilogue
#define Q_SCALE 0.18033688011112042f

__device__ __forceinline__ void async16(const void* g, void* l) {
  // 16B-wide global->LDS DMA; LDS dest is wave-uniform base + lane*16
  __builtin_amdgcn_global_load_lds((AS1 void*)g, (AS3 void*)l, 16, 0, 0);
}

__device__ __forceinline__ u16 f2bf(float f) {  // RNE float->bf16
  union { float f; unsigned int u; } v; v.f = f;
  unsigned int u = v.u;
  u += 0x7fffu + ((u >> 16) & 1u);
  return (u16)(u >> 16);
}

__device__ __forceinline__ unsigned int u32of(float f) {
  union { float f; unsigned int u; } v; v.f = f; return v.u;
}

// pack hi16(a)|hi16(b)<<16 in one v_perm_b32 (truncating f32->bf16 pair)
__device__ __forceinline__ unsigned int pack_trunc(float a, float b) {
  return __builtin_amdgcn_perm(u32of(b), u32of(a), 0x07060302u);
}

// native v_exp_f32: computes 2^x
__device__ __forceinline__ float exp2_fast(float x) {
  return __builtin_amdgcn_exp2f(x);
}

// fast GELU (tanh form), ~12 VALU ops, no libm
__device__ __forceinline__ float gelu_f(float x) {
  const float y = 0.7978845608028654f * (x + 0.044715f * x * x * x);
  // tanh(y) = 1 - 2/(1 + 2^(y*2*log2(e)))
  const float e = exp2_fast(y * 2.885390081777927f);
  const float t = 1.0f - 2.0f * __builtin_amdgcn_rcpf(1.0f + e);
  return 0.5f * x * (1.0f + t);
}

// ---------------- all-weights fp32 -> bf16 convert (one launch) ----------------
// Region boundaries are multiples of 1024 elements -> no intra-block divergence.
__global__ __launch_bounds__(256) void cvt_all(const float* __restrict__ a, u16* __restrict__ oa, int na,
                                               const float* __restrict__ b, u16* __restrict__ ob, int nb,
                                               const float* __restrict__ c, u16* __restrict__ oc, int nc,
                                               const float* __restrict__ d, u16* __restrict__ od) {
  int i = (blockIdx.x * 256 + threadIdx.x) * 4;
  const float* src;
  u16* dst;
  if (i < na) { src = a; dst = oa; }
  else if ((i -= na) < nb) { src = b; dst = ob; }
  else if ((i -= nb) < nc) { src = c; dst = oc; }
  else { i -= nc; src = d; dst = od; }
  const float4 v = *(const float4*)(src + i);
  dst[i + 0] = f2bf(v.x); dst[i + 1] = f2bf(v.y);
  dst[i + 2] = f2bf(v.z); dst[i + 3] = f2bf(v.w);
}

// ---------------- LayerNorm (row of 1024) -> bf16 ----------------
__global__ __launch_bounds__(256) void ln_bf16(const float* __restrict__ x,
                                               const float* __restrict__ g,
                                               const float* __restrict__ bta,
                                               u16* __restrict__ outp) {
  const int row = blockIdx.x;
  const int tid = threadIdx.x;
  const float4 v = *(const float4*)(x + (size_t)row * EDIM + tid * 4);
  float s = v.x + v.y + v.z + v.w;
  float ss = v.x * v.x + v.y * v.y + v.z * v.z + v.w * v.w;
#pragma unroll
  for (int o = 1; o < 64; o <<= 1) {
    s += __shfl_xor(s, o);
    ss += __shfl_xor(ss, o);
  }
  __shared__ float red[8];
  const int wave = tid >> 6, lane = tid & 63;
  if (lane == 0) { red[wave] = s; red[4 + wave] = ss; }
  __syncthreads();
  s = red[0] + red[1] + red[2] + red[3];
  ss = red[4] + red[5] + red[6] + red[7];
  const float mu = s * (1.0f / 1024.0f);
  const float var = ss * (1.0f / 1024.0f) - mu * mu;
  const float inv = rsqrtf(var + 1e-5f);
  const float4 gv = *(const float4*)(g + tid * 4);
  const float4 bv = *(const float4*)(bta + tid * 4);
  u16* od = outp + (size_t)row * EDIM + tid * 4;
  od[0] = f2bf((v.x - mu) * inv * gv.x + bv.x);
  od[1] = f2bf((v.y - mu) * inv * gv.y + bv.y);
  od[2] = f2bf((v.z - mu) * inv * gv.z + bv.z);
  od[3] = f2bf((v.w - mu) * inv * gv.w + bv.w);
}

// ---------------- NT GEMM (proven 2-barrier structure): BMx128, BK=64, 8 waves ----
// T1 XCD-affine remap (proven R5: 508->483): all nx col-blocks of one row-panel
// time-adjacent on ONE XCD so the shared A-panel hits that XCD's L2.
// Bijective for gridDim.y%8==0.
template <int EPI, int BM = 256>
__global__ __launch_bounds__(512) void gemm_bt(const u16* __restrict__ A,
                                               const u16* __restrict__ Bw,
                                               void* __restrict__ Cout,
                                               const float* __restrict__ bias,
                                               const float* __restrict__ res,
                                               int M, int N, int K) {
  constexpr int IB = BM / 64;        // acc rows per wave: 256->4, 128->2
  constexpr int WROWS = BM / 4;      // rows per wave band: 256->64, 128->32
  __shared__ __align__(16) u16 As[BM * 64];    // 32 KB (BM=256) / 16 KB (BM=128)
  __shared__ __align__(16) u16 Bs[128 * 64];   // 16 KB
  const int tid = threadIdx.x;
  const int lane = tid & 63;
  const int wave = tid >> 6;      // 0..7
  const int quad = lane >> 4;
  const int cl = lane & 15;

  // ---- T1: XCD-affine bijective block remap (requires gridDim.y % 8 == 0) ----
  const int nx = gridDim.x;
  const int f = blockIdx.y * nx + blockIdx.x;   // dispatch-linear id
  const int xcd = f & 7;                        // HW round-robin XCD
  const int uu = f >> 3;
  const int rows_per = gridDim.y >> 3;          // row-panels per XCD
  const int bxy = xcd * rows_per + uu / nx;     // row-panel (col-blocks adjacent)
  const int bxx = uu % nx;                      // col-block

  const int row0 = bxy * BM;
  const int col0 = bxx * 128;
  const int wm = wave >> 1;       // 0..3: WROWS-row band
  const int wn = wave & 1;        // 0..1: 64-col band

  floatx4 acc[IB][4];
#pragma unroll
  for (int i = 0; i < IB; ++i)
#pragma unroll
    for (int j = 0; j < 4; ++j) acc[i][j] = (floatx4){0.f, 0.f, 0.f, 0.f};

  // staging: chunk c = p*512 + tid; row = p*64 + (tid>>3); LDS slot = tid&7;
  // global chunk gc = (tid&7) ^ ((tid>>3)&7)  (p-independent since p adds 64 rows).
  const int trow = tid >> 3;               // 0..63
  const int gc = (tid & 7) ^ (trow & 7);
  const u16* Ath = A + (size_t)(row0 + trow) * K + gc * 8;
  const u16* Bth = Bw + (size_t)(col0 + trow) * K + gc * 8;
  u16* lA = As + tid * 8;                  // + p*4096
  u16* lB = Bs + tid * 8;
  const size_t pstride = (size_t)64 * K;   // 64 rows per p

  for (int k0 = 0; k0 < K; k0 += 64) {
    __syncthreads();
#pragma unroll
    for (int p = 0; p < BM / 64; ++p)
      async16(Ath + p * pstride + k0, lA + p * 4096);
#pragma unroll
    for (int p = 0; p < 2; ++p)
      async16(Bth + p * pstride + k0, lB + p * 4096);
    __syncthreads();
#pragma unroll
    for (int s = 0; s < 2; ++s) {
      const int ko = ((s * 4 + quad) ^ (cl & 7)) * 8;
      short8 af[IB], bfr[4];
#pragma unroll
      for (int i = 0; i < IB; ++i)
        af[i] = *(const short8*)(As + (wm * WROWS + i * 16 + cl) * 64 + ko);
#pragma unroll
      for (int j = 0; j < 4; ++j)
        bfr[j] = *(const short8*)(Bs + (wn * 64 + j * 16 + cl) * 64 + ko);
#pragma unroll
      for (int i = 0; i < IB; ++i)
#pragma unroll
        for (int j = 0; j < 4; ++j)
          acc[i][j] = __builtin_amdgcn_mfma_f32_16x16x32_bf16(af[i], bfr[j], acc[i][j], 0, 0, 0);
    }
  }

  const float qscale = (EPI == 5 && col0 < 1024) ? Q_SCALE : 1.0f;
#pragma unroll
  for (int i = 0; i < IB; ++i) {
#pragma unroll
    for (int r = 0; r < 4; ++r) {
      const int row = row0 + wm * WROWS + i * 16 + quad * 4 + r;
#pragma unroll
      for (int j = 0; j < 4; ++j) {
        const int col = col0 + wn * 64 + j * 16 + cl;
        const size_t idx = (size_t)row * N + col;
        float v = acc[i][j][r];
        if (EPI == 0) {
          ((float*)Cout)[idx] = v;
        } else if (EPI == 1 || EPI == 3) {
          ((float*)Cout)[idx] = v + bias[col] + res[idx];
        } else if (EPI == 2) {
          ((u16*)Cout)[idx] = f2bf(gelu_f(v + bias[col]));
        } else if (EPI == 4) {
          ((u16*)Cout)[idx] = f2bf(v);
        } else if (EPI == 5) {
          ((u16*)Cout)[idx] = f2bf(v * qscale);
        }
      }
    }
  }
}

// ---------------- NT GEMM 8-phase v2: 256xBN tile, BK=64, 512 threads, dbuf LDS ----
// R4 post-mortem fixes (counter-driven):
//  (a) R4's gemm8 had NO XCD remap -> FETCH 282MB @2.7TB/s = L2-locality-bound
//      (the schedule was condemned on confounded evidence). Now has T1 remap.
//  (b) Prefetch issues were spread across phases 0..2 with the drain at phase 3
//      of the SAME tile -> last-issued load had <1 phase (~150cy) cover vs ~900cy
//      HBM. Now ALL 2xREG issues consolidated at phase 0 -> min cover = 3 full
//      phases (~850cy) of ds_read+MFMA. Single vmcnt(0) drain per tile (phase 3).
// Functionally identical accumulation to R4's gemm8 (which PASSED, absmax .094).
template <int EPI, int BN>
__global__ __launch_bounds__(512, 2) void gemm8(const u16* __restrict__ A,
                                                const u16* __restrict__ Bw,
                                                void* __restrict__ Cout,
                                                const float* __restrict__ bias,
                                                const float* __restrict__ res,
                                                int M, int N, int K) {
  constexpr int BHALF = BN / 128;        // B half-tiles: 2 (BN=256) or 1 (BN=128)
  constexpr int REG = 2 + BHALF;         // LDS regions per dbuf (A0,A1,B0[,B1])
  constexpr int NF = BN / 64;            // n-frags per wave: 4 or 2
  constexpr int DBS = REG * 8192;        // u16 per dbuf
  __shared__ __align__(16) u16 lds[2 * REG * 8192];  // 128 KB / 96 KB

  const int tid = threadIdx.x;
  const int lane = tid & 63;
  const int wave = tid >> 6;      // 0..7
  const int quad = lane >> 4;
  const int cl = lane & 15;
  const int wm = wave >> 2;       // 0..1: 128-row band
  const int wn = wave & 3;        // 0..3: (BN/4)-col band

  // ---- T1: XCD-affine bijective block remap (requires gridDim.y % 8 == 0) ----
  const int nx = gridDim.x;
  const int f = blockIdx.y * nx + blockIdx.x;
  const int xcd = f & 7;
  const int uu = f >> 3;
  const int rows_per = gridDim.y >> 3;
  const int row0 = (xcd * rows_per + uu / nx) * 256;
  const int col0 = (uu % nx) * BN;

  // staging map (chunk-XOR, proven): thread covers rows i*64+trow of a region
  const int trow = tid >> 3;               // 0..63
  const int gc = (tid & 7) ^ (trow & 7);
  const size_t aoff = (size_t)(row0 + trow) * K + gc * 8;
  const size_t boff = (size_t)(col0 + trow) * K + gc * 8;
  const size_t rstride = (size_t)128 * K;  // region (128 rows)
  const size_t hstride = (size_t)64 * K;   // i-step (64 rows)

  // frag read bases (u16 offsets within a dbuf)
  const int aro = wm * 8192 + cl * 64;
  const int bro = (BN == 256) ? ((2 + (wn >> 1)) * 8192 + ((wn & 1) * 64 + cl) * 64)
                              : (2 * 8192 + (wn * 32 + cl) * 64);
  const int ko0 = ((0 + quad) ^ (cl & 7)) * 8;
  const int ko1 = ((4 + quad) ^ (cl & 7)) * 8;

  floatx4 acc[8][NF];
#pragma unroll
  for (int i = 0; i < 8; ++i)
#pragma unroll
    for (int j = 0; j < NF; ++j) acc[i][j] = (floatx4){0.f, 0.f, 0.f, 0.f};

  const int nt = K >> 6;

  // prologue: stage tile 0 into dbuf 0, drain, barrier
#pragma unroll
  for (int r = 0; r < REG; ++r) {
    const u16* s0 = (r < 2) ? (A + aoff + (size_t)r * rstride)
                            : (Bw + boff + (size_t)(r - 2) * rstride);
    async16(s0, lds + r * 8192 + tid * 8);
    async16(s0 + hstride, lds + r * 8192 + 4096 + tid * 8);
  }
  asm volatile("s_waitcnt vmcnt(0)" ::: "memory");
  __builtin_amdgcn_s_barrier();
  __builtin_amdgcn_sched_barrier(0);

  short8 bf[NF][2];  // B-frags persist across the 4 sub-phases of a tile

  for (int t = 0; t < nt; ++t) {
    u16* cb = lds + (t & 1) * DBS;
    u16* nb = lds + ((t + 1) & 1) * DBS;
    const int kn = (t + 1) * 64;        // next tile k-col offset (u16)
    const bool more = (t + 1 < nt);
#pragma unroll
    for (int q = 0; q < 4; ++q) {
      // ---- ds_reads from current buffer ----
      short8 a00 = *(const short8*)(cb + aro + (2 * q + 0) * 1024 + ko0);
      short8 a01 = *(const short8*)(cb + aro + (2 * q + 0) * 1024 + ko1);
      short8 a10 = *(const short8*)(cb + aro + (2 * q + 1) * 1024 + ko0);
      short8 a11 = *(const short8*)(cb + aro + (2 * q + 1) * 1024 + ko1);
      if (q == 0) {
#pragma unroll
        for (int n = 0; n < NF; ++n) {
          bf[n][0] = *(const short8*)(cb + bro + n * 1024 + ko0);
          bf[n][1] = *(const short8*)(cb + bro + n * 1024 + ko1);
        }
        // ---- issue ALL of next tile's loads here (max drain cover) ----
        if (more) {
#pragma unroll
          for (int r = 0; r < REG; ++r) {
            const u16* s0 = (r < 2) ? (A + aoff + (size_t)r * rstride + kn)
                                    : (Bw + boff + (size_t)(r - 2) * rstride + kn);
            async16(s0, nb + r * 8192 + tid * 8);
            async16(s0 + hstride, nb + r * 8192 + 4096 + tid * 8);
          }
        }
      }
      __builtin_amdgcn_s_barrier();
      asm volatile("s_waitcnt lgkmcnt(0)" ::: "memory");
      __builtin_amdgcn_sched_barrier(0);
      __builtin_amdgcn_s_setprio(1);
#pragma unroll
      for (int n = 0; n < NF; ++n) {
        acc[2 * q + 0][n] = __builtin_amdgcn_mfma_f32_16x16x32_bf16(a00, bf[n][0], acc[2 * q + 0][n], 0, 0, 0);
        acc[2 * q + 0][n] = __builtin_amdgcn_mfma_f32_16x16x32_bf16(a01, bf[n][1], acc[2 * q + 0][n], 0, 0, 0);
        acc[2 * q + 1][n] = __builtin_amdgcn_mfma_f32_16x16x32_bf16(a10, bf[n][0], acc[2 * q + 1][n], 0, 0, 0);
        acc[2 * q + 1][n] = __builtin_amdgcn_mfma_f32_16x16x32_bf16(a11, bf[n][1], acc[2 * q + 1][n], 0, 0, 0);
      }
      __builtin_amdgcn_s_setprio(0);
      if (q == 3) { asm volatile("s_waitcnt vmcnt(0)" ::: "memory"); }
      __builtin_amdgcn_s_barrier();
      __builtin_amdgcn_sched_barrier(0);
    }
  }

  const float qscale = (EPI == 5 && col0 < 1024) ? Q_SCALE : 1.0f;
#pragma unroll
  for (int i = 0; i < 8; ++i) {
#pragma unroll
    for (int r = 0; r < 4; ++r) {
      const int row = row0 + wm * 128 + i * 16 + quad * 4 + r;
#pragma unroll
      for (int j = 0; j < NF; ++j) {
        const int col = col0 + wn * (BN / 4) + j * 16 + cl;
        const size_t idx = (size_t)row * N + col;
        float v = acc[i][j][r];
        if (EPI == 0) {
          ((float*)Cout)[idx] = v;
        } else if (EPI == 1 || EPI == 3) {
          ((float*)Cout)[idx] = v + bias[col] + res[idx];
        } else if (EPI == 2) {
          ((u16*)Cout)[idx] = f2bf(gelu_f(v + bias[col]));
        } else if (EPI == 4) {
          ((u16*)Cout)[idx] = f2bf(v);
        } else if (EPI == 5) {
          ((u16*)Cout)[idx] = f2bf(v * qscale);
        }
      }
    }
  }
}

// ---------------- V transpose: qkv bf16 [tok][3072] -> vt[b,h][d][s] bf16 ----------------
__global__ __launch_bounds__(256) void vtrans(const u16* __restrict__ qkv,
                                              u16* __restrict__ vt) {
  __shared__ unsigned int T[64 * 65];
  const int tid = threadIdx.x;
  const int bh = blockIdx.y;
  const int b = bh >> 4;
  const int h = bh & 15;
  const int s0 = blockIdx.x * 64;
#pragma unroll
  for (int pp = 0; pp < 2; ++pp) {
    const int g = pp * 256 + tid;
    const int r = g >> 3;
    const int d0 = (g & 7) * 8;
    const u16* src = qkv + (size_t)(b * SEQ + s0 + r) * 3072 + 2048 + h * 64 + d0;
    short8 v = *(const short8*)src;
#pragma unroll
    for (int i = 0; i < 8; ++i) T[(d0 + i) * 65 + r] = (u16)v[i];
  }
  __syncthreads();
#pragma unroll
  for (int pp = 0; pp < 2; ++pp) {
    const int g = pp * 256 + tid;
    const int d = g >> 3;
    const int sc = (g & 7) * 8;
    short8 v;
#pragma unroll
    for (int i = 0; i < 8; ++i) v[i] = (short)(u16)T[d * 65 + sc + i];
    *(short8*)(vt + ((size_t)bh * 64 + d) * SEQ + s0 + sc) = v;
  }
}

// ---------------- MFMA flash attention v3 (FROZEN — proven) ----------------
__global__ __launch_bounds__(256, 4) void attn3(const u16* __restrict__ qkv,
                                                const u16* __restrict__ vt,
                                                u16* __restrict__ outp) {
  __shared__ __align__(16) u16 smem[8192 + 8192 + 4 * 32 * 72];  // Ks | Vs | P (51.2 KB)
  u16* Ks = smem;            // [128 kv][64 d], chunk-swizzled ^(row&7)
  u16* Vs = smem + 8192;     // [64 d][128 kv], chunk-swizzled ^(row&15)
  const int tid = threadIdx.x;
  const int lane = tid & 63;
  const int wave = tid >> 6;
  const int quad = lane >> 4;
  const int cl = lane & 15;

  // XCD-affine swizzle: all 16 q-blocks of one (b,h) on one XCD, adjacent in time
  const int f = blockIdx.y * 16 + blockIdx.x;
  const int xcd = f & 7;
  const int u = f >> 3;
  const int qi = u & 15;
  const int bh = xcd * 8 + (u >> 4);
  const int b = bh >> 4;
  const int h = bh & 15;
  const int q0 = qi * 128;
  u16* Pw = smem + 16384 + wave * (32 * 72);  // P[q=32][kv=64], stride 72

  const u16* qbase = qkv + (size_t)(b * SEQ) * 3072 + h * 64;
  const u16* kbase = qbase + 1024;
  const u16* vbase = vt + (size_t)bh * 64 * SEQ;

  // ---- stage Q tile (128 x 64) swizzled into Ks region ----
#pragma unroll
  for (int p = 0; p < 4; ++p) {
    const int g = (wave * 4 + p) * 64 + lane;
    const int r = g >> 3;
    const int c = (g & 7) ^ (r & 7);
    async16(qbase + (size_t)(q0 + r) * 3072 + c * 8, smem + g * 8);
  }
  __syncthreads();
  short8 qf[2][2];  // B-frag [n=q][k=d]
#pragma unroll
  for (int ng = 0; ng < 2; ++ng)
#pragma unroll
    for (int kc = 0; kc < 2; ++kc) {
      const int row = wave * 32 + ng * 16 + cl;
      qf[ng][kc] = *(const short8*)(smem + row * 64 + (((kc * 4 + quad) ^ (cl & 7)) * 8));
    }

  floatx4 O[4][2];  // [d-group][q-group]
  float lrun[2] = {0.f, 0.f};
#pragma unroll
  for (int mg = 0; mg < 4; ++mg)
#pragma unroll
    for (int ng = 0; ng < 2; ++ng) O[mg][ng] = (floatx4){0.f, 0.f, 0.f, 0.f};

  for (int kt = 0; kt < SEQ / 128; ++kt) {
    const int k0 = kt * 128;
    __syncthreads();  // previous tile consumed (iter 0: qf loaded)
    const u16* kb = kbase + (size_t)k0 * 3072;
#pragma unroll
    for (int p = 0; p < 2; ++p) {
      const int g = wave * 128 + p * 64 + lane;
      const int rk = g >> 3;
      const int ck = (g & 7) ^ (rk & 7);
      async16(kb + (size_t)rk * 3072 + ck * 8, Ks + g * 8);
      const int rv = g >> 4;
      const int cv = (g & 15) ^ (rv & 15);
      async16(vbase + (size_t)rv * SEQ + k0 + cv * 8, Vs + g * 8);
    }
    __syncthreads();  // all tiles landed (vmcnt drained at barrier)

#pragma unroll
    for (int s = 0; s < 2; ++s) {
      // ---- S^T = K Q^T ----
      floatx4 Sc[4][2];
#pragma unroll
      for (int mg = 0; mg < 4; ++mg)
#pragma unroll
        for (int ng = 0; ng < 2; ++ng) Sc[mg][ng] = (floatx4){0.f, 0.f, 0.f, 0.f};
#pragma unroll
      for (int kc = 0; kc < 2; ++kc) {
        short8 kf[4];
#pragma unroll
        for (int mg = 0; mg < 4; ++mg) {
          const int row = s * 64 + mg * 16 + cl;
          kf[mg] = *(const short8*)(Ks + row * 64 + (((kc * 4 + quad) ^ (cl & 7)) * 8));
        }
#pragma unroll
        for (int mg = 0; mg < 4; ++mg)
#pragma unroll
          for (int ng = 0; ng < 2; ++ng)
            Sc[mg][ng] = __builtin_amdgcn_mfma_f32_16x16x32_bf16(kf[mg], qf[ng][kc], Sc[mg][ng], 0, 0, 0);
      }

      // ---- no-max softmax: P = 2^S (Q prescaled); l += sum ----
#pragma unroll
      for (int ng = 0; ng < 2; ++ng) {
        float rs = 0.f;
#pragma unroll
        for (int mg = 0; mg < 4; ++mg)
#pragma unroll
          for (int r = 0; r < 4; ++r) {
            const float pv = exp2_fast(Sc[mg][ng][r]);
            Sc[mg][ng][r] = pv;
            rs += pv;
          }
        rs += __shfl_xor(rs, 16);
        rs += __shfl_xor(rs, 32);
        lrun[ng] += rs;
      }

      // ---- P pack (truncating perm) + b64 store, wave-private ----
#pragma unroll
      for (int mg = 0; mg < 4; ++mg)
#pragma unroll
        for (int ng = 0; ng < 2; ++ng) {
          const unsigned int lo = pack_trunc(Sc[mg][ng][0], Sc[mg][ng][1]);
          const unsigned int hi = pack_trunc(Sc[mg][ng][2], Sc[mg][ng][3]);
          *(uint2*)(Pw + (ng * 16 + cl) * 72 + mg * 16 + quad * 4) = make_uint2(lo, hi);
        }

      // ---- O^T += V^T P^T ----
#pragma unroll
      for (int kc = 0; kc < 2; ++kc) {
        short8 pf[2], vf[4];
#pragma unroll
        for (int ng = 0; ng < 2; ++ng)
          pf[ng] = *(const short8*)(Pw + (ng * 16 + cl) * 72 + kc * 32 + quad * 8);
#pragma unroll
        for (int mg = 0; mg < 4; ++mg) {
          const int row = mg * 16 + cl;
          vf[mg] = *(const short8*)(Vs + row * 128 + (((s * 8 + kc * 4 + quad) ^ (cl & 15)) * 8));
        }
#pragma unroll
        for (int mg = 0; mg < 4; ++mg)
#pragma unroll
          for (int ng = 0; ng < 2; ++ng)
            O[mg][ng] = __builtin_amdgcn_mfma_f32_16x16x32_bf16(vf[mg], pf[ng], O[mg][ng], 0, 0, 0);
      }
    }
  }

  // ---- epilogue: O^T[d][q] / l -> out[q][h*64+d] ----
#pragma unroll
  for (int ng = 0; ng < 2; ++ng) {
    const float inv = 1.0f / lrun[ng];
    const int qrow = q0 + wave * 32 + ng * 16 + cl;
    u16* od = outp + (size_t)(b * SEQ + qrow) * EDIM + h * 64;
#pragma unroll
    for (int mg = 0; mg < 4; ++mg) {
      const unsigned int lo = (unsigned int)f2bf(O[mg][ng][0] * inv) |
                              ((unsigned int)f2bf(O[mg][ng][1] * inv) << 16);
      const unsigned int hi = (unsigned int)f2bf(O[mg][ng][2] * inv) |
                              ((unsigned int)f2bf(O[mg][ng][3] * inv) << 16);
      *(uint2*)(od + mg * 16 + quad * 4) = make_uint2(lo, hi);
    }
  }
}

// ---------------- launcher ----------------
extern "C" void kernel_launch(void* const* d_in, const int* in_sizes, int n_in,
                              void* d_out, int out_size, void* d_ws, size_t ws_size,
                              hipStream_t stream) {
  const float* x    = (const float*)d_in[0];
  const float* qkvw = (const float*)d_in[1];
  const float* fcw  = (const float*)d_in[2];
  const float* fcb  = (const float*)d_in[3];
  const float* ln1g = (const float*)d_in[4];
  const float* ln1b = (const float*)d_in[5];
  const float* ln2g = (const float*)d_in[6];
  const float* ln2b = (const float*)d_in[7];
  const float* w1   = (const float*)d_in[8];
  const float* b1   = (const float*)d_in[9];
  const float* w2   = (const float*)d_in[10];
  const float* b2   = (const float*)d_in[11];

  char* ws = (char*)d_ws;
  size_t off = 0;
  u16* wqkv = (u16*)(ws + off); off += (size_t)3 * EDIM * EDIM * 2;   // 6 MB
  u16* wfc  = (u16*)(ws + off); off += (size_t)EDIM * EDIM * 2;       // 2 MB
  u16* w1b  = (u16*)(ws + off); off += (size_t)MLPD * EDIM * 2;       // 8 MB
  u16* w2b  = (u16*)(ws + off); off += (size_t)EDIM * MLPD * 2;       // 8 MB
  u16* hbuf = (u16*)(ws + off); off += (size_t)ROWS * EDIM * 2;       // 16 MB
  u16* aout = (u16*)(ws + off); off += (size_t)ROWS * EDIM * 2;       // 16 MB
  float* x2 = (float*)(ws + off); off += (size_t)ROWS * EDIM * 4;     // 32 MB
  u16* qkvb = (u16*)(ws + off); off += (size_t)ROWS * 3 * EDIM * 2;   // 48 MB (bf16)
  u16* vtb  = (u16*)(ws + off); off += (size_t)ROWS * EDIM * 2;       // 16 MB
  u16* hmlp = qkvb;  // reuse qkvb+vtb (64 MB) for MLP hidden after attention

  // all weights -> bf16 in one launch
  cvt_all<<<12288, 256, 0, stream>>>(qkvw, wqkv, 3 * EDIM * EDIM,
                                     fcw, wfc, EDIM * EDIM,
                                     w1, w1b, MLPD * EDIM,
                                     w2, w2b);

  // attention sublayer
  ln_bf16<<<ROWS, 256, 0, stream>>>(x, ln1g, ln1b, hbuf);
  gemm8<5, 256><<<dim3(12, 32), 512, 0, stream>>>(hbuf, wqkv, qkvb, nullptr, nullptr,
                                                  ROWS, 3 * EDIM, EDIM);
  vtrans<<<dim3(SEQ / 64, 64), 256, 0, stream>>>(qkvb, vtb);
  attn3<<<dim3(16, 64), 256, 0, stream>>>(qkvb, vtb, aout);
  gemm_bt<1, 128><<<dim3(8, 64), 512, 0, stream>>>(aout, wfc, x2, fcb, x,
                                                   ROWS, EDIM, EDIM);
  // MLP sublayer
  ln_bf16<<<ROWS, 256, 0, stream>>>(x2, ln2g, ln2b, hbuf);
  gemm8<2, 256><<<dim3(16, 32), 512, 0, stream>>>(hbuf, w1b, hmlp, b1, nullptr,
                                                  ROWS, MLPD, EDIM);
  gemm8<3, 128><<<dim3(8, 32), 512, 0, stream>>>(hmlp, w2b, (float*)d_out, b2, x2,
                                                 ROWS, EDIM, MLPD);
}

// Round 7
// 480.289 us; speedup vs baseline: 1.0408x; 1.0408x over previous
//
#include <hip/hip_runtime.h>
#include <cstdint>
#include <cmath>

// Problem constants
#define EDIM 1024
#define SEQ 2048
#define BATCH 4
#define NHEAD 16
#define HDIM 64
#define MLPD 4096
#define ROWS 8192  // BATCH*SEQ

typedef unsigned short u16;
typedef __attribute__((ext_vector_type(8))) short short8;   // 8 bf16 = 4 VGPRs (MFMA A/B frag)
typedef __attribute__((ext_vector_type(4))) float floatx4;  // MFMA C/D frag

#define AS1 __attribute__((address_space(1)))
#define AS3 __attribute__((address_space(3)))

// exp(s*0.125) = 2^(s*0.125*log2e); fold scale into Q at GEMM epilogue
#define Q_SCALE 0.18033688011112042f

__device__ __forceinline__ void async16(const void* g, void* l) {
  // 16B-wide global->LDS DMA; LDS dest is wave-uniform base + lane*16
  __builtin_amdgcn_global_load_lds((AS1 void*)g, (AS3 void*)l, 16, 0, 0);
}

__device__ __forceinline__ u16 f2bf(float f) {  // RNE float->bf16
  union { float f; unsigned int u; } v; v.f = f;
  unsigned int u = v.u;
  u += 0x7fffu + ((u >> 16) & 1u);
  return (u16)(u >> 16);
}

__device__ __forceinline__ unsigned int u32of(float f) {
  union { float f; unsigned int u; } v; v.f = f; return v.u;
}

// pack hi16(a)|hi16(b)<<16 in one v_perm_b32 (truncating f32->bf16 pair)
__device__ __forceinline__ unsigned int pack_trunc(float a, float b) {
  return __builtin_amdgcn_perm(u32of(b), u32of(a), 0x07060302u);
}

// native v_exp_f32: computes 2^x
__device__ __forceinline__ float exp2_fast(float x) {
  return __builtin_amdgcn_exp2f(x);
}

// fast GELU (tanh form), ~12 VALU ops, no libm
__device__ __forceinline__ float gelu_f(float x) {
  const float y = 0.7978845608028654f * (x + 0.044715f * x * x * x);
  // tanh(y) = 1 - 2/(1 + 2^(y*2*log2(e)))
  const float e = exp2_fast(y * 2.885390081777927f);
  const float t = 1.0f - 2.0f * __builtin_amdgcn_rcpf(1.0f + e);
  return 0.5f * x * (1.0f + t);
}

// ---------------- all-weights fp32 -> bf16 convert (one launch) ----------------
// Region boundaries are multiples of 1024 elements -> no intra-block divergence.
__global__ __launch_bounds__(256) void cvt_all(const float* __restrict__ a, u16* __restrict__ oa, int na,
                                               const float* __restrict__ b, u16* __restrict__ ob, int nb,
                                               const float* __restrict__ c, u16* __restrict__ oc, int nc,
                                               const float* __restrict__ d, u16* __restrict__ od) {
  int i = (blockIdx.x * 256 + threadIdx.x) * 4;
  const float* src;
  u16* dst;
  if (i < na) { src = a; dst = oa; }
  else if ((i -= na) < nb) { src = b; dst = ob; }
  else if ((i -= nb) < nc) { src = c; dst = oc; }
  else { i -= nc; src = d; dst = od; }
  const float4 v = *(const float4*)(src + i);
  dst[i + 0] = f2bf(v.x); dst[i + 1] = f2bf(v.y);
  dst[i + 2] = f2bf(v.z); dst[i + 3] = f2bf(v.w);
}

// ---------------- LayerNorm (row of 1024) -> bf16 ----------------
__global__ __launch_bounds__(256) void ln_bf16(const float* __restrict__ x,
                                               const float* __restrict__ g,
                                               const float* __restrict__ bta,
                                               u16* __restrict__ outp) {
  const int row = blockIdx.x;
  const int tid = threadIdx.x;
  const float4 v = *(const float4*)(x + (size_t)row * EDIM + tid * 4);
  float s = v.x + v.y + v.z + v.w;
  float ss = v.x * v.x + v.y * v.y + v.z * v.z + v.w * v.w;
#pragma unroll
  for (int o = 1; o < 64; o <<= 1) {
    s += __shfl_xor(s, o);
    ss += __shfl_xor(ss, o);
  }
  __shared__ float red[8];
  const int wave = tid >> 6, lane = tid & 63;
  if (lane == 0) { red[wave] = s; red[4 + wave] = ss; }
  __syncthreads();
  s = red[0] + red[1] + red[2] + red[3];
  ss = red[4] + red[5] + red[6] + red[7];
  const float mu = s * (1.0f / 1024.0f);
  const float var = ss * (1.0f / 1024.0f) - mu * mu;
  const float inv = rsqrtf(var + 1e-5f);
  const float4 gv = *(const float4*)(g + tid * 4);
  const float4 bv = *(const float4*)(bta + tid * 4);
  u16* od = outp + (size_t)row * EDIM + tid * 4;
  od[0] = f2bf((v.x - mu) * inv * gv.x + bv.x);
  od[1] = f2bf((v.y - mu) * inv * gv.y + bv.y);
  od[2] = f2bf((v.z - mu) * inv * gv.z + bv.z);
  od[3] = f2bf((v.w - mu) * inv * gv.w + bv.w);
}

// ---------------- NT GEMM (proven 2-barrier structure): BMx128, BKx, 8 waves ------
// T1 XCD-affine remap (proven R5: 508->483): all nx col-blocks of one row-panel
// time-adjacent on ONE XCD so the shared A-panel hits that XCD's L2.
// Bijective for gridDim.y%8==0.
// BK template param (R7): for the grid-limited 2-block/CU GEMMs (fc, w2 at
// BM=128, grid 512), BK=128 keeps residency (64KB LDS -> still 2/CU) while
// HALVING the exposed per-iteration drain-barrier events (w2: 64->32, fc:
// 16->8). Staging map generalizes: CPR=BK/8 chunks/row, 512/CPR rows/pass,
// XOR swizzle slot=chunk^(row&7) unchanged (rows/pass multiple of 8).
// Accumulation k-order identical -> bitwise-same results as BK=64.
// EPI: 0 = store fp32
//      1/3 = fp32 store of (acc + bias[col] + res[idx])
//      2 = bf16 store of gelu(acc + bias[col])
//      4 = bf16 store of acc
//      5 = bf16 store of acc * (col<1024 ? Q_SCALE : 1)  (qkv GEMM, prescaled Q)
template <int EPI, int BM = 256, int BK = 64>
__global__ __launch_bounds__(512) void gemm_bt(const u16* __restrict__ A,
                                               const u16* __restrict__ Bw,
                                               void* __restrict__ Cout,
                                               const float* __restrict__ bias,
                                               const float* __restrict__ res,
                                               int M, int N, int K) {
  constexpr int IB = BM / 64;        // acc rows per wave: 256->4, 128->2
  constexpr int WROWS = BM / 4;      // rows per wave band: 256->64, 128->32
  constexpr int CPR = BK / 8;        // 16B chunks per row: 8 (BK=64) / 16 (BK=128)
  constexpr int ROWSP = 512 / CPR;   // rows staged per pass: 64 / 32
  constexpr int PA = BM / ROWSP;     // A staging passes
  constexpr int PB = 128 / ROWSP;    // B staging passes
  constexpr int S = BK / 32;         // k sub-steps per tile: 2 / 4
  __shared__ __align__(16) u16 As[BM * BK];
  __shared__ __align__(16) u16 Bs[128 * BK];
  const int tid = threadIdx.x;
  const int lane = tid & 63;
  const int wave = tid >> 6;      // 0..7
  const int quad = lane >> 4;
  const int cl = lane & 15;

  // ---- T1: XCD-affine bijective block remap (requires gridDim.y % 8 == 0) ----
  const int nx = gridDim.x;
  const int f = blockIdx.y * nx + blockIdx.x;   // dispatch-linear id
  const int xcd = f & 7;                        // HW round-robin XCD
  const int uu = f >> 3;
  const int rows_per = gridDim.y >> 3;          // row-panels per XCD
  const int bxy = xcd * rows_per + uu / nx;     // row-panel (col-blocks adjacent)
  const int bxx = uu % nx;                      // col-block

  const int row0 = bxy * BM;
  const int col0 = bxx * 128;
  const int wm = wave >> 1;       // 0..3: WROWS-row band
  const int wn = wave & 1;        // 0..1: 64-col band

  floatx4 acc[IB][4];
#pragma unroll
  for (int i = 0; i < IB; ++i)
#pragma unroll
    for (int j = 0; j < 4; ++j) acc[i][j] = (floatx4){0.f, 0.f, 0.f, 0.f};

  // staging: chunk c = p*512 + tid; row = p*ROWSP + (tid/CPR); LDS slot = tid%CPR;
  // global chunk gc = (tid%CPR) ^ (row&7)  (p-independent since ROWSP%8==0).
  const int trow = tid / CPR;
  const int gc = (tid % CPR) ^ (trow & 7);
  const u16* Ath = A + (size_t)(row0 + trow) * K + gc * 8;
  const u16* Bth = Bw + (size_t)(col0 + trow) * K + gc * 8;
  u16* lA = As + tid * 8;                  // + p*4096
  u16* lB = Bs + tid * 8;
  const size_t pstride = (size_t)ROWSP * K;

  for (int k0 = 0; k0 < K; k0 += BK) {
    __syncthreads();
#pragma unroll
    for (int p = 0; p < PA; ++p)
      async16(Ath + p * pstride + k0, lA + p * 4096);
#pragma unroll
    for (int p = 0; p < PB; ++p)
      async16(Bth + p * pstride + k0, lB + p * 4096);
    __syncthreads();
#pragma unroll
    for (int s = 0; s < S; ++s) {
      const int ko = ((s * 4 + quad) ^ (cl & 7)) * 8;
      short8 af[IB], bfr[4];
#pragma unroll
      for (int i = 0; i < IB; ++i)
        af[i] = *(const short8*)(As + (wm * WROWS + i * 16 + cl) * BK + ko);
#pragma unroll
      for (int j = 0; j < 4; ++j)
        bfr[j] = *(const short8*)(Bs + (wn * 64 + j * 16 + cl) * BK + ko);
#pragma unroll
      for (int i = 0; i < IB; ++i)
#pragma unroll
        for (int j = 0; j < 4; ++j)
          acc[i][j] = __builtin_amdgcn_mfma_f32_16x16x32_bf16(af[i], bfr[j], acc[i][j], 0, 0, 0);
    }
  }

  const float qscale = (EPI == 5 && col0 < 1024) ? Q_SCALE : 1.0f;
#pragma unroll
  for (int i = 0; i < IB; ++i) {
#pragma unroll
    for (int r = 0; r < 4; ++r) {
      const int row = row0 + wm * WROWS + i * 16 + quad * 4 + r;
#pragma unroll
      for (int j = 0; j < 4; ++j) {
        const int col = col0 + wn * 64 + j * 16 + cl;
        const size_t idx = (size_t)row * N + col;
        float v = acc[i][j][r];
        if (EPI == 0) {
          ((float*)Cout)[idx] = v;
        } else if (EPI == 1 || EPI == 3) {
          ((float*)Cout)[idx] = v + bias[col] + res[idx];
        } else if (EPI == 2) {
          ((u16*)Cout)[idx] = f2bf(gelu_f(v + bias[col]));
        } else if (EPI == 4) {
          ((u16*)Cout)[idx] = f2bf(v);
        } else if (EPI == 5) {
          ((u16*)Cout)[idx] = f2bf(v * qscale);
        }
      }
    }
  }
}

// ---------------- V transpose: qkv bf16 [tok][3072] -> vt[b,h][d][s] bf16 ----------------
__global__ __launch_bounds__(256) void vtrans(const u16* __restrict__ qkv,
                                              u16* __restrict__ vt) {
  __shared__ unsigned int T[64 * 65];
  const int tid = threadIdx.x;
  const int bh = blockIdx.y;
  const int b = bh >> 4;
  const int h = bh & 15;
  const int s0 = blockIdx.x * 64;
#pragma unroll
  for (int pp = 0; pp < 2; ++pp) {
    const int g = pp * 256 + tid;
    const int r = g >> 3;
    const int d0 = (g & 7) * 8;
    const u16* src = qkv + (size_t)(b * SEQ + s0 + r) * 3072 + 2048 + h * 64 + d0;
    short8 v = *(const short8*)src;
#pragma unroll
    for (int i = 0; i < 8; ++i) T[(d0 + i) * 65 + r] = (u16)v[i];
  }
  __syncthreads();
#pragma unroll
  for (int pp = 0; pp < 2; ++pp) {
    const int g = pp * 256 + tid;
    const int d = g >> 3;
    const int sc = (g & 7) * 8;
    short8 v;
#pragma unroll
    for (int i = 0; i < 8; ++i) v[i] = (short)(u16)T[d * 65 + sc + i];
    *(short8*)(vt + ((size_t)bh * 64 + d) * SEQ + s0 + sc) = v;
  }
}

// ---------------- MFMA flash attention v3 (FROZEN — proven) ----------------
__global__ __launch_bounds__(256, 4) void attn3(const u16* __restrict__ qkv,
                                                const u16* __restrict__ vt,
                                                u16* __restrict__ outp) {
  __shared__ __align__(16) u16 smem[8192 + 8192 + 4 * 32 * 72];  // Ks | Vs | P (51.2 KB)
  u16* Ks = smem;            // [128 kv][64 d], chunk-swizzled ^(row&7)
  u16* Vs = smem + 8192;     // [64 d][128 kv], chunk-swizzled ^(row&15)
  const int tid = threadIdx.x;
  const int lane = tid & 63;
  const int wave = tid >> 6;
  const int quad = lane >> 4;
  const int cl = lane & 15;

  // XCD-affine swizzle: all 16 q-blocks of one (b,h) on one XCD, adjacent in time
  const int f = blockIdx.y * 16 + blockIdx.x;
  const int xcd = f & 7;
  const int u = f >> 3;
  const int qi = u & 15;
  const int bh = xcd * 8 + (u >> 4);
  const int b = bh >> 4;
  const int h = bh & 15;
  const int q0 = qi * 128;
  u16* Pw = smem + 16384 + wave * (32 * 72);  // P[q=32][kv=64], stride 72

  const u16* qbase = qkv + (size_t)(b * SEQ) * 3072 + h * 64;
  const u16* kbase = qbase + 1024;
  const u16* vbase = vt + (size_t)bh * 64 * SEQ;

  // ---- stage Q tile (128 x 64) swizzled into Ks region ----
#pragma unroll
  for (int p = 0; p < 4; ++p) {
    const int g = (wave * 4 + p) * 64 + lane;
    const int r = g >> 3;
    const int c = (g & 7) ^ (r & 7);
    async16(qbase + (size_t)(q0 + r) * 3072 + c * 8, smem + g * 8);
  }
  __syncthreads();
  short8 qf[2][2];  // B-frag [n=q][k=d]
#pragma unroll
  for (int ng = 0; ng < 2; ++ng)
#pragma unroll
    for (int kc = 0; kc < 2; ++kc) {
      const int row = wave * 32 + ng * 16 + cl;
      qf[ng][kc] = *(const short8*)(smem + row * 64 + (((kc * 4 + quad) ^ (cl & 7)) * 8));
    }

  floatx4 O[4][2];  // [d-group][q-group]
  float lrun[2] = {0.f, 0.f};
#pragma unroll
  for (int mg = 0; mg < 4; ++mg)
#pragma unroll
    for (int ng = 0; ng < 2; ++ng) O[mg][ng] = (floatx4){0.f, 0.f, 0.f, 0.f};

  for (int kt = 0; kt < SEQ / 128; ++kt) {
    const int k0 = kt * 128;
    __syncthreads();  // previous tile consumed (iter 0: qf loaded)
    const u16* kb = kbase + (size_t)k0 * 3072;
#pragma unroll
    for (int p = 0; p < 2; ++p) {
      const int g = wave * 128 + p * 64 + lane;
      const int rk = g >> 3;
      const int ck = (g & 7) ^ (rk & 7);
      async16(kb + (size_t)rk * 3072 + ck * 8, Ks + g * 8);
      const int rv = g >> 4;
      const int cv = (g & 15) ^ (rv & 15);
      async16(vbase + (size_t)rv * SEQ + k0 + cv * 8, Vs + g * 8);
    }
    __syncthreads();  // all tiles landed (vmcnt drained at barrier)

#pragma unroll
    for (int s = 0; s < 2; ++s) {
      // ---- S^T = K Q^T ----
      floatx4 Sc[4][2];
#pragma unroll
      for (int mg = 0; mg < 4; ++mg)
#pragma unroll
        for (int ng = 0; ng < 2; ++ng) Sc[mg][ng] = (floatx4){0.f, 0.f, 0.f, 0.f};
#pragma unroll
      for (int kc = 0; kc < 2; ++kc) {
        short8 kf[4];
#pragma unroll
        for (int mg = 0; mg < 4; ++mg) {
          const int row = s * 64 + mg * 16 + cl;
          kf[mg] = *(const short8*)(Ks + row * 64 + (((kc * 4 + quad) ^ (cl & 7)) * 8));
        }
#pragma unroll
        for (int mg = 0; mg < 4; ++mg)
#pragma unroll
          for (int ng = 0; ng < 2; ++ng)
            Sc[mg][ng] = __builtin_amdgcn_mfma_f32_16x16x32_bf16(kf[mg], qf[ng][kc], Sc[mg][ng], 0, 0, 0);
      }

      // ---- no-max softmax: P = 2^S (Q prescaled); l += sum ----
#pragma unroll
      for (int ng = 0; ng < 2; ++ng) {
        float rs = 0.f;
#pragma unroll
        for (int mg = 0; mg < 4; ++mg)
#pragma unroll
          for (int r = 0; r < 4; ++r) {
            const float pv = exp2_fast(Sc[mg][ng][r]);
            Sc[mg][ng][r] = pv;
            rs += pv;
          }
        rs += __shfl_xor(rs, 16);
        rs += __shfl_xor(rs, 32);
        lrun[ng] += rs;
      }

      // ---- P pack (truncating perm) + b64 store, wave-private ----
#pragma unroll
      for (int mg = 0; mg < 4; ++mg)
#pragma unroll
        for (int ng = 0; ng < 2; ++ng) {
          const unsigned int lo = pack_trunc(Sc[mg][ng][0], Sc[mg][ng][1]);
          const unsigned int hi = pack_trunc(Sc[mg][ng][2], Sc[mg][ng][3]);
          *(uint2*)(Pw + (ng * 16 + cl) * 72 + mg * 16 + quad * 4) = make_uint2(lo, hi);
        }

      // ---- O^T += V^T P^T ----
#pragma unroll
      for (int kc = 0; kc < 2; ++kc) {
        short8 pf[2], vf[4];
#pragma unroll
        for (int ng = 0; ng < 2; ++ng)
          pf[ng] = *(const short8*)(Pw + (ng * 16 + cl) * 72 + kc * 32 + quad * 8);
#pragma unroll
        for (int mg = 0; mg < 4; ++mg) {
          const int row = mg * 16 + cl;
          vf[mg] = *(const short8*)(Vs + row * 128 + (((s * 8 + kc * 4 + quad) ^ (cl & 15)) * 8));
        }
#pragma unroll
        for (int mg = 0; mg < 4; ++mg)
#pragma unroll
          for (int ng = 0; ng < 2; ++ng)
            O[mg][ng] = __builtin_amdgcn_mfma_f32_16x16x32_bf16(vf[mg], pf[ng], O[mg][ng], 0, 0, 0);
      }
    }
  }

  // ---- epilogue: O^T[d][q] / l -> out[q][h*64+d] ----
#pragma unroll
  for (int ng = 0; ng < 2; ++ng) {
    const float inv = 1.0f / lrun[ng];
    const int qrow = q0 + wave * 32 + ng * 16 + cl;
    u16* od = outp + (size_t)(b * SEQ + qrow) * EDIM + h * 64;
#pragma unroll
    for (int mg = 0; mg < 4; ++mg) {
      const unsigned int lo = (unsigned int)f2bf(O[mg][ng][0] * inv) |
                              ((unsigned int)f2bf(O[mg][ng][1] * inv) << 16);
      const unsigned int hi = (unsigned int)f2bf(O[mg][ng][2] * inv) |
                              ((unsigned int)f2bf(O[mg][ng][3] * inv) << 16);
      *(uint2*)(od + mg * 16 + quad * 4) = make_uint2(lo, hi);
    }
  }
}

// ---------------- launcher ----------------
extern "C" void kernel_launch(void* const* d_in, const int* in_sizes, int n_in,
                              void* d_out, int out_size, void* d_ws, size_t ws_size,
                              hipStream_t stream) {
  const float* x    = (const float*)d_in[0];
  const float* qkvw = (const float*)d_in[1];
  const float* fcw  = (const float*)d_in[2];
  const float* fcb  = (const float*)d_in[3];
  const float* ln1g = (const float*)d_in[4];
  const float* ln1b = (const float*)d_in[5];
  const float* ln2g = (const float*)d_in[6];
  const float* ln2b = (const float*)d_in[7];
  const float* w1   = (const float*)d_in[8];
  const float* b1   = (const float*)d_in[9];
  const float* w2   = (const float*)d_in[10];
  const float* b2   = (const float*)d_in[11];

  char* ws = (char*)d_ws;
  size_t off = 0;
  u16* wqkv = (u16*)(ws + off); off += (size_t)3 * EDIM * EDIM * 2;   // 6 MB
  u16* wfc  = (u16*)(ws + off); off += (size_t)EDIM * EDIM * 2;       // 2 MB
  u16* w1b  = (u16*)(ws + off); off += (size_t)MLPD * EDIM * 2;       // 8 MB
  u16* w2b  = (u16*)(ws + off); off += (size_t)EDIM * MLPD * 2;       // 8 MB
  u16* hbuf = (u16*)(ws + off); off += (size_t)ROWS * EDIM * 2;       // 16 MB
  u16* aout = (u16*)(ws + off); off += (size_t)ROWS * EDIM * 2;       // 16 MB
  float* x2 = (float*)(ws + off); off += (size_t)ROWS * EDIM * 4;     // 32 MB
  u16* qkvb = (u16*)(ws + off); off += (size_t)ROWS * 3 * EDIM * 2;   // 48 MB (bf16)
  u16* vtb  = (u16*)(ws + off); off += (size_t)ROWS * EDIM * 2;       // 16 MB
  u16* hmlp = qkvb;  // reuse qkvb+vtb (64 MB) for MLP hidden after attention

  // all weights -> bf16 in one launch
  cvt_all<<<12288, 256, 0, stream>>>(qkvw, wqkv, 3 * EDIM * EDIM,
                                     fcw, wfc, EDIM * EDIM,
                                     w1, w1b, MLPD * EDIM,
                                     w2, w2b);

  // attention sublayer
  ln_bf16<<<ROWS, 256, 0, stream>>>(x, ln1g, ln1b, hbuf);
  gemm_bt<5><<<dim3(24, 32), 512, 0, stream>>>(hbuf, wqkv, qkvb, nullptr, nullptr,
                                               ROWS, 3 * EDIM, EDIM);
  vtrans<<<dim3(SEQ / 64, 64), 256, 0, stream>>>(qkvb, vtb);
  attn3<<<dim3(16, 64), 256, 0, stream>>>(qkvb, vtb, aout);
  gemm_bt<1, 128, 128><<<dim3(8, 64), 512, 0, stream>>>(aout, wfc, x2, fcb, x,
                                                        ROWS, EDIM, EDIM);
  // MLP sublayer
  ln_bf16<<<ROWS, 256, 0, stream>>>(x2, ln2g, ln2b, hbuf);
  gemm_bt<2><<<dim3(32, 32), 512, 0, stream>>>(hbuf, w1b, hmlp, b1, nullptr,
                                               ROWS, MLPD, EDIM);
  gemm_bt<3, 128, 128><<<dim3(8, 64), 512, 0, stream>>>(hmlp, w2b, (float*)d_out, b2, x2,
                                                        ROWS, EDIM, MLPD);
}